// Round 2
// 637.540 us; speedup vs baseline: 1.0206x; 1.0206x over previous
//
#include <hip/hip_runtime.h>

#define IN_CH 128
#define HEADS 4
#define OUT_CH 32
#define HC 128           // HEADS*OUT_CH
#define SCORE_BLOCKS 4096
#define CHUNK 2048       // scan chunk (256 thr x 8)

__device__ __forceinline__ unsigned flip_f32(float x) {
  unsigned u = __float_as_uint(x);
  return (u & 0x80000000u) ? ~u : (u | 0x80000000u);
}
__device__ __forceinline__ float unflip_f32(unsigned k) {
  unsigned u = (k & 0x80000000u) ? (k ^ 0x80000000u) : ~k;
  return __uint_as_float(u);
}
__device__ __forceinline__ float fast_tanh(float x) {
  return 1.f - 2.f / (__expf(2.f * x) + 1.f);
}

// proj[N][128] = x[N][128] @ W[128][128]
__global__ __launch_bounds__(256) void gemm_xW(const float* __restrict__ x,
                                               const float* __restrict__ W,
                                               float* __restrict__ proj, int N) {
  __shared__ float xs[128][132];
  __shared__ float ws[128][128];
  const int tid = threadIdx.x;
  const int row0 = blockIdx.x * 128;

  {
    const float4* Wv = (const float4*)W;
    float4* wsv = (float4*)ws;
#pragma unroll
    for (int i = 0; i < 16; ++i) wsv[i * 256 + tid] = Wv[i * 256 + tid];
  }
  {
    const int r = tid >> 1;
    const int k0 = (tid & 1) * 64;
    const int grow = row0 + r;
    const bool valid = grow < N;
    const float4* src = (const float4*)(x + (size_t)grow * IN_CH + k0);
#pragma unroll
    for (int i = 0; i < 16; ++i) {
      float4 v = valid ? src[i] : make_float4(0.f, 0.f, 0.f, 0.f);
      const int k = k0 + i * 4;
      xs[k][r] = v.x; xs[k + 1][r] = v.y; xs[k + 2][r] = v.z; xs[k + 3][r] = v.w;
    }
  }
  __syncthreads();

  const int cg = tid & 15;
  const int rg = tid >> 4;
  float acc[8][8];
#pragma unroll
  for (int r = 0; r < 8; ++r)
#pragma unroll
    for (int c = 0; c < 8; ++c) acc[r][c] = 0.f;

#pragma unroll 4
  for (int k = 0; k < 128; ++k) {
    float4 a0 = *(const float4*)&xs[k][rg * 8];
    float4 a1 = *(const float4*)&xs[k][rg * 8 + 4];
    float4 b0 = *(const float4*)&ws[k][cg * 8];
    float4 b1 = *(const float4*)&ws[k][cg * 8 + 4];
    float xv[8] = {a0.x, a0.y, a0.z, a0.w, a1.x, a1.y, a1.z, a1.w};
    float wv[8] = {b0.x, b0.y, b0.z, b0.w, b1.x, b1.y, b1.z, b1.w};
#pragma unroll
    for (int r = 0; r < 8; ++r)
#pragma unroll
      for (int c = 0; c < 8; ++c) acc[r][c] += xv[r] * wv[c];
  }

#pragma unroll
  for (int r = 0; r < 8; ++r) {
    const int grow = row0 + rg * 8 + r;
    if (grow < N) {
      float4* dst = (float4*)(proj + (size_t)grow * HC + cg * 8);
      dst[0] = make_float4(acc[r][0], acc[r][1], acc[r][2], acc[r][3]);
      dst[1] = make_float4(acc[r][4], acc[r][5], acc[r][6], acc[r][7]);
    }
  }
}

// histogram over exact destination node
__global__ __launch_bounds__(256) void edge_hist(const int* __restrict__ ecol,
                                                 int* __restrict__ hist, int E) {
  const int i = blockIdx.x * 256 + threadIdx.x;
  if (i < E) atomicAdd(&hist[ecol[i]], 1);
}

// --- hierarchical exclusive scan over nb counters ---
__device__ __forceinline__ int block_scan_excl(int tsum, int* ls, int tid, int* total) {
  ls[tid] = tsum;
  __syncthreads();
  for (int off = 1; off < 256; off <<= 1) {
    int v = (tid >= off) ? ls[tid - off] : 0;
    __syncthreads();
    ls[tid] += v;
    __syncthreads();
  }
  *total = ls[255];
  return ls[tid] - tsum;
}

__global__ __launch_bounds__(256) void k_scan_a(const int* __restrict__ hist,
                                                int* __restrict__ sums, int nb) {
  __shared__ int ls[256];
  const int tid = threadIdx.x;
  const int base = blockIdx.x * CHUNK + tid * 8;
  int t = 0;
#pragma unroll
  for (int j = 0; j < 8; ++j) { const int i = base + j; if (i < nb) t += hist[i]; }
  int total;
  block_scan_excl(t, ls, tid, &total);
  if (tid == 0) sums[blockIdx.x] = total;
}

__global__ __launch_bounds__(256) void k_scan_b(int* __restrict__ sums, int nc,
                                                int* __restrict__ starts,
                                                int* __restrict__ cursor, int nb) {
  __shared__ int ls[256];
  const int tid = threadIdx.x;
  const int t = (tid < nc) ? sums[tid] : 0;
  int total;
  const int excl = block_scan_excl(t, ls, tid, &total);
  if (tid < nc) sums[tid] = excl;
  if (tid == 0) { starts[nb] = total; cursor[nb] = total; }
}

__global__ __launch_bounds__(256) void k_scan_c(const int* __restrict__ hist,
                                                const int* __restrict__ sums,
                                                int* __restrict__ starts,
                                                int* __restrict__ cursor, int nb) {
  __shared__ int ls[256];
  const int tid = threadIdx.x;
  const int base = blockIdx.x * CHUNK + tid * 8;
  int t = 0;
#pragma unroll
  for (int j = 0; j < 8; ++j) { const int i = base + j; if (i < nb) t += hist[i]; }
  int total;
  const int excl = block_scan_excl(t, ls, tid, &total);
  int run = sums[blockIdx.x] + excl;
#pragma unroll
  for (int j = 0; j < 8; ++j) {
    const int i = base + j;
    if (i < nb) { starts[i] = run; cursor[i] = run; run += hist[i]; }
  }
}

// CSR permutation: rc[p] = src row, records grouped by dst node.
__global__ __launch_bounds__(256) void scatter_rc(const int* __restrict__ erow,
                                                  const int* __restrict__ ecol,
                                                  int* __restrict__ cursor,
                                                  int* __restrict__ rc, int E) {
  const int i = blockIdx.x * 256 + threadIdx.x;
  if (i < E) {
    const int p = atomicAdd(&cursor[ecol[i]], 1);
    rc[p] = erow[i];
  }
}

// One wave per dst node: gather each src row ONCE, compute score + weight +
// value accumulation in registers. Stabilizer = analytic bound M0_h = sum|att[h]|
// (scale cancels in the ratio). Also tracks per-block true score max and writes
// per-(node,head) denominator so fix_clamp can reproduce the reference's
// max(normalizer,1e-12) semantics EXACTLY afterward.
__global__ __launch_bounds__(256) void fused_apply(const float* __restrict__ proj,
                                                   const int* __restrict__ rc,
                                                   const int* __restrict__ starts,
                                                   const float* __restrict__ att,
                                                   float* __restrict__ out,
                                                   float* __restrict__ den,
                                                   unsigned* __restrict__ blockmax, int N) {
  __shared__ unsigned blkmax[HEADS];
  const int tid = threadIdx.x;
  if (tid < HEADS) blkmax[tid] = 0u;
  __syncthreads();
  const int lane = tid & 63;
  const int n = blockIdx.x * 4 + (tid >> 6);
  float lmA = -3.0e38f, lmB = -3.0e38f;

  if (n < N) {
    const float a0 = att[lane];        // heads 0/1 (by lane>>5)
    const float a1 = att[lane + 64];   // heads 2/3
    float M0 = fabsf(a0), M1 = fabsf(a1);
#pragma unroll
    for (int m = 16; m >= 1; m >>= 1) {
      M0 += __shfl_xor(M0, m, 64);
      M1 += __shfl_xor(M1, m, 64);
    }
    const float* pd = proj + (size_t)n * HC;
    const float d0 = pd[lane];
    const float d1 = pd[lane + 64];
    const int beg = starts[n];
    const int end = starts[n + 1];

    float acc0 = 0.f, acc1 = 0.f, den0 = 0.f, den1 = 0.f;
    int i = beg;
    for (; i + 4 <= end; i += 4) {
      int rows[4];
#pragma unroll
      for (int u = 0; u < 4; ++u) rows[u] = rc[i + u];
      float s0[4], s1[4];
#pragma unroll
      for (int u = 0; u < 4; ++u) {
        const float* ps = proj + (size_t)rows[u] * HC;
        s0[u] = ps[lane];
        s1[u] = ps[lane + 64];
      }
#pragma unroll
      for (int u = 0; u < 4; ++u) {
        float pA = fast_tanh(s0[u] + d0) * a0;
        float pB = fast_tanh(s1[u] + d1) * a1;
#pragma unroll
        for (int m = 16; m >= 1; m >>= 1) {
          pA += __shfl_xor(pA, m, 64);
          pB += __shfl_xor(pB, m, 64);
        }
        lmA = fmaxf(lmA, pA);
        lmB = fmaxf(lmB, pB);
        const float e0 = __expf(pA - M0);
        const float e1 = __expf(pB - M1);
        acc0 += s0[u] * e0; den0 += e0;
        acc1 += s1[u] * e1; den1 += e1;
      }
    }
    for (; i < end; ++i) {
      const int row = rc[i];
      const float* ps = proj + (size_t)row * HC;
      const float sv0 = ps[lane];
      const float sv1 = ps[lane + 64];
      float pA = fast_tanh(sv0 + d0) * a0;
      float pB = fast_tanh(sv1 + d1) * a1;
#pragma unroll
      for (int m = 16; m >= 1; m >>= 1) {
        pA += __shfl_xor(pA, m, 64);
        pB += __shfl_xor(pB, m, 64);
      }
      lmA = fmaxf(lmA, pA);
      lmB = fmaxf(lmB, pB);
      const float e0 = __expf(pA - M0);
      const float e1 = __expf(pB - M1);
      acc0 += sv0 * e0; den0 += e0;
      acc1 += sv1 * e1; den1 += e1;
    }
    out[(size_t)n * HC + lane] = acc0 / fmaxf(den0, 1e-38f);
    out[(size_t)n * HC + 64 + lane] = acc1 / fmaxf(den1, 1e-38f);
    if (lane == 0)  { den[n * HEADS + 0] = den0; den[n * HEADS + 2] = den1; }
    if (lane == 32) { den[n * HEADS + 1] = den0; den[n * HEADS + 3] = den1; }
  }
  if ((lane & 31) == 0) {
    const int hh = lane >> 5;
    atomicMax(&blkmax[hh], flip_f32(lmA));
    atomicMax(&blkmax[hh + 2], flip_f32(lmB));
  }
  __syncthreads();
  if (tid < HEADS) blockmax[blockIdx.x * HEADS + tid] = blkmax[tid];
}

// blockmax -> true per-head max Mt; corr[h] = exp(M0_h - Mt_h), corr[4+h] = Mt_h.
__global__ __launch_bounds__(256) void reduce_corr(const unsigned* __restrict__ blockmax,
                                                   const float* __restrict__ att,
                                                   float* __restrict__ corr, int nblk) {
  __shared__ unsigned sm[HEADS];
  const int tid = threadIdx.x;
  if (tid < HEADS) sm[tid] = 0u;
  __syncthreads();
  const int h = tid & 3;
  unsigned k = 0u;
  for (int i = tid >> 2; i < nblk; i += 64) k = max(k, blockmax[i * HEADS + h]);
  atomicMax(&sm[h], k);
  __syncthreads();
  if (tid < HEADS) {
    const float Mt = unflip_f32(sm[tid]);
    float M0 = 0.f;
#pragma unroll
    for (int c = 0; c < OUT_CH; ++c) M0 += fabsf(att[tid * OUT_CH + c]);
    corr[tid] = __expf(M0 - Mt);
    corr[4 + tid] = Mt;
  }
}

// Reference normalizer = den * corr[h]. If it is below 1e-12, the reference
// clamps: out_ref = out_ours * (ref_den / 1e-12). Apply that correction.
__global__ __launch_bounds__(256) void fix_clamp(float* __restrict__ out,
                                                 const float* __restrict__ den,
                                                 const float* __restrict__ corr, int N) {
  const int t = blockIdx.x * 256 + threadIdx.x;
  if (t >= N * HEADS) return;
  const int n = t >> 2;
  const int h = t & 3;
  const float f = den[t] * corr[h];
  if (f < 1e-12f) {
    const float s = f * 1e12f;
    float4* p = (float4*)(out + (size_t)n * HC + h * OUT_CH);
#pragma unroll
    for (int j = 0; j < 8; ++j) {
      float4 v = p[j];
      v.x *= s; v.y *= s; v.z *= s; v.w *= s;
      p[j] = v;
    }
  }
}

// --- fallback path (ws too small): score-max pass + edge-parallel atomics ---
__global__ __launch_bounds__(256) void score_max(const float* __restrict__ proj,
                                                 const int* __restrict__ erow,
                                                 const int* __restrict__ ecol,
                                                 const float* __restrict__ att,
                                                 unsigned* __restrict__ blockmax, int E) {
  __shared__ unsigned blkmax[HEADS];
  const int tid = threadIdx.x;
  if (tid < HEADS) blkmax[tid] = 0u;
  __syncthreads();
  const int lane = tid & 63;
  const int wid = tid >> 6;
  const float a0 = att[lane];
  const float a1 = att[lane + 64];
  float lmA = -3.0e38f, lmB = -3.0e38f;
  const int stride = SCORE_BLOCKS * 16;

  for (int base = (blockIdx.x * 4 + wid) * 4; base < E; base += stride) {
    const int bu = __builtin_amdgcn_readfirstlane(base);
    const int lim = min(bu + 4, E);
    for (int e = bu; e < lim; ++e) {
      const int r0 = erow[e], c0 = ecol[e];
      const float* ps = proj + (size_t)r0 * HC;
      const float* pd = proj + (size_t)c0 * HC;
      float pA = fast_tanh(ps[lane] + pd[lane]) * a0;
      float pB = fast_tanh(ps[lane + 64] + pd[lane + 64]) * a1;
#pragma unroll
      for (int m = 16; m >= 1; m >>= 1) {
        pA += __shfl_xor(pA, m, 64);
        pB += __shfl_xor(pB, m, 64);
      }
      lmA = fmaxf(lmA, pA);
      lmB = fmaxf(lmB, pB);
    }
  }
  if ((lane & 31) == 0) {
    const int hh = lane >> 5;
    atomicMax(&blkmax[hh], flip_f32(lmA));
    atomicMax(&blkmax[hh + 2], flip_f32(lmB));
  }
  __syncthreads();
  if (tid < HEADS) blockmax[blockIdx.x * HEADS + tid] = blkmax[tid];
}

__global__ __launch_bounds__(256) void edge_apply_fb(const float* __restrict__ proj,
                                                     const int* __restrict__ erow,
                                                     const int* __restrict__ ecol,
                                                     const float* __restrict__ att,
                                                     const float* __restrict__ headmax,
                                                     float* __restrict__ out,
                                                     float* __restrict__ norm, int E) {
  const int tid = threadIdx.x;
  const int e = blockIdx.x * 2 + (tid >> 7);
  if (e >= E) return;
  const int ch = tid & 127;
  const int h = ch >> 5;
  const float M = headmax[h];
  const int row = erow[e];
  const int col = ecol[e];
  const float sv = proj[(size_t)row * HC + ch];
  const float dv = proj[(size_t)col * HC + ch];
  float p = fast_tanh(sv + dv) * att[ch];
#pragma unroll
  for (int m = 16; m >= 1; m >>= 1) p += __shfl_xor(p, m, 64);
  const float w = __expf(p - M);
  unsafeAtomicAdd(&out[(size_t)col * HC + ch], sv * w);
  if ((ch & 31) == 0) unsafeAtomicAdd(&norm[(size_t)col * HEADS + h], w);
}

__global__ __launch_bounds__(256) void finalize_fb(float* __restrict__ out,
                                                   const float* __restrict__ norm, int N) {
  const int idx = blockIdx.x * blockDim.x + threadIdx.x;
  const int total = N * (HC / 4);
  if (idx >= total) return;
  const int base = idx * 4;
  const int node = base >> 7;
  const int h = (base >> 5) & 3;
  const float inv = 1.f / fmaxf(norm[node * HEADS + h], 1e-12f);
  float4 v = ((float4*)out)[idx];
  v.x *= inv; v.y *= inv; v.z *= inv; v.w *= inv;
  ((float4*)out)[idx] = v;
}

extern "C" void kernel_launch(void* const* d_in, const int* in_sizes, int n_in,
                              void* d_out, int out_size, void* d_ws, size_t ws_size,
                              hipStream_t stream) {
  const float* x    = (const float*)d_in[0];
  const int*   eidx = (const int*)d_in[1];  // [2][E]: row(src) then col(dst)
  const float* W    = (const float*)d_in[2];
  const float* att  = (const float*)d_in[3];
  float* out = (float*)d_out;

  const int N = in_sizes[0] / IN_CH;
  const int E = in_sizes[1] / 2;
  const int nb = N;
  const int nc = (nb + CHUNK - 1) / CHUNK;  // scan chunks (<=256 supported)
  const int nblkf = (N + 3) / 4;            // fused_apply grid

  // ws layout (16B-aligned pieces)
  char* p = (char*)d_ws;
  float* proj = (float*)p;            p += (size_t)N * HC * 4;
  int* rc = (int*)p;                  p += (((size_t)E * 4 + 15) & ~15ull);
  float* den = (float*)p;             p += (((size_t)N * HEADS * 4 + 15) & ~15ull);
  unsigned* blockmax = (unsigned*)p;  p += (((size_t)nblkf * HEADS * 4 + 15) & ~15ull);
  float* corr = (float*)p;            p += 32;
  int* hist = (int*)p;                p += (((size_t)nb * 4 + 15) & ~15ull);
  int* starts = (int*)p;              p += (((size_t)(nb + 1) * 4 + 15) & ~15ull);
  int* cursor = (int*)p;              p += (((size_t)(nb + 1) * 4 + 15) & ~15ull);
  int* sums = (int*)p;                p += 1024;
  const size_t need_full = (size_t)(p - (char*)d_ws);
  const bool full = (ws_size >= need_full) && (nc <= 256);

  gemm_xW<<<(N + 127) / 128, 256, 0, stream>>>(x, W, proj, N);

  if (full) {
    hipMemsetAsync(hist, 0, (size_t)nb * sizeof(int), stream);
    edge_hist<<<(E + 255) / 256, 256, 0, stream>>>(eidx + E, hist, E);
    k_scan_a<<<nc, 256, 0, stream>>>(hist, sums, nb);
    k_scan_b<<<1, 256, 0, stream>>>(sums, nc, starts, cursor, nb);
    k_scan_c<<<nc, 256, 0, stream>>>(hist, sums, starts, cursor, nb);
    scatter_rc<<<(E + 255) / 256, 256, 0, stream>>>(eidx, eidx + E, cursor, rc, E);
    fused_apply<<<nblkf, 256, 0, stream>>>(proj, rc, starts, att, out, den, blockmax, N);
    reduce_corr<<<1, 256, 0, stream>>>(blockmax, att, corr, nblkf);
    fix_clamp<<<(N * HEADS + 255) / 256, 256, 0, stream>>>(out, den, corr, N);
  } else {
    // minimal-ws fallback: blockmax/corr/norm packed right after proj
    unsigned* bm = (unsigned*)(proj + (size_t)N * HC);
    float* cr = (float*)(bm + SCORE_BLOCKS * HEADS);
    float* norm = cr + 8;
    hipMemsetAsync(out, 0, (size_t)out_size * sizeof(float), stream);
    hipMemsetAsync(norm, 0, (size_t)N * HEADS * sizeof(float), stream);
    score_max<<<SCORE_BLOCKS, 256, 0, stream>>>(proj, eidx, eidx + E, att, bm, E);
    reduce_corr<<<1, 256, 0, stream>>>(bm, att, cr, SCORE_BLOCKS);
    edge_apply_fb<<<(E + 1) / 2, 256, 0, stream>>>(proj, eidx, eidx + E, att, cr + 4, out, norm, E);
    finalize_fb<<<(N * (HC / 4) + 255) / 256, 256, 0, stream>>>(out, norm, N);
  }
}